// Round 8
// baseline (303.897 us; speedup 1.0000x reference)
//
#include <hip/hip_runtime.h>

#define B_ 32
#define CD 128
#define O3 384
#define N  4096
#define H_ 4
#define C_ 32

typedef __bf16 bf16x8 __attribute__((ext_vector_type(8)));
typedef float floatx4 __attribute__((ext_vector_type(4)));

#define MFMA16(a, b, c) __builtin_amdgcn_mfma_f32_16x16x32_bf16(a, b, c, 0, 0, 0)

__device__ __forceinline__ float b2f(unsigned int u) {   // low 16 bits
  return __builtin_bit_cast(float, u << 16);
}
__device__ __forceinline__ float b2fh(unsigned int u) {  // high 16 bits
  return __builtin_bit_cast(float, u & 0xffff0000u);
}
__device__ __forceinline__ unsigned short f2b(float f) {
  unsigned int bits = __builtin_bit_cast(unsigned int, f);
  unsigned int r = (bits + 0x7FFFu + ((bits >> 16) & 1u)) >> 16;
  return (unsigned short)r;
}

// ---------------------------------------------------------------------------
// K0: transpose+convert x [b][c][n] fp32 -> xT [b][n][c] bf16.
// NEW layout: block = 32-n strip x ALL 128 c -> each block stores 32 rows of
// 256B = 8KB fully contiguous (full cache lines; the old version emitted 64B
// chunks at 256B stride -> partial-line write-allocate).
// LDS [128][33] f32, scalar writes/reads: <=2-way banks both phases.
// Side-work on the y==0 plane: weight conversions (wid<66), qk coefficient
// tables (wid==66), part2 zeroing (wid 67..127). grid (128, 32), 256 thr.
// ---------------------------------------------------------------------------
__global__ __launch_bounds__(256) void k0_xt(
    const float* __restrict__ x, unsigned short* __restrict__ xT,
    const float* __restrict__ qkv_w, const float* __restrict__ proj_w,
    const float* __restrict__ dw_w, const float* __restrict__ dw_b,
    const float* __restrict__ qkv_b,
    unsigned short* __restrict__ qkv_wb, unsigned short* __restrict__ proj_wb,
    float4* __restrict__ dwq, float4* __restrict__ dwq2,
    float* __restrict__ c0a, float* __restrict__ c2a,
    float* __restrict__ part2)
{
  __shared__ float xt[128 * 33];
  const int t = threadIdx.x;
  const int ns = blockIdx.x * 32, b = blockIdx.y;
  const float* xb = x + (size_t)b * CD * N + ns;

  // ---- side work (y==0 plane) ----
  if (blockIdx.y == 0) {
    int wid = blockIdx.x;
    if (wid < 66) {
      int e = (wid * 256 + t) * 4;
      if (e < 49152) {
        float4 v = *(const float4*)(qkv_w + e);
        unsigned short tmp[4] = {f2b(v.x), f2b(v.y), f2b(v.z), f2b(v.w)};
        *(uint2*)(qkv_wb + e) = *(uint2*)tmp;
      } else if (e < 65536) {
        int off = e - 49152;
        float4 v = *(const float4*)(proj_w + off);
        unsigned short tmp[4] = {f2b(v.x), f2b(v.y), f2b(v.z), f2b(v.w)};
        *(uint2*)(proj_wb + off) = *(uint2*)tmp;
      } else {
        int o = (e - 65536) >> 2;
        if (o < 384)
          dwq[o] = make_float4(dw_w[o * 9 + 1], dw_w[o * 9 + 4],
                               dw_w[o * 9 + 7], dw_b[o]);
      }
    } else if (wid == 66) {
      int o = t;    // 256 threads cover q,k channels 0..255
      float w0 = dw_w[o * 9 + 1], w1 = dw_w[o * 9 + 4], w2 = dw_w[o * 9 + 7];
      float qb = qkv_b[o];
      dwq2[o] = make_float4(w0, w1, w2, qb * (w0 + w1 + w2) + dw_b[o]);
      c0a[o] = qb * w0;
      c2a[o] = qb * w2;
    } else {      // wid 67..127: zero part2 (34816 uint4)
      int idx = (wid - 67) * 256 + t;
      uint4 z4 = make_uint4(0u, 0u, 0u, 0u);
      for (int k2 = idx; k2 < 34816; k2 += 61 * 256)
        ((uint4*)part2)[k2] = z4;
    }
  }

  // ---- load 128 c-rows x 32 n (float4 per lane, 4 passes) ----
#pragma unroll
  for (int p = 0; p < 4; p++) {
    int c = p * 32 + (t >> 3), n4 = (t & 7) * 4;
    float4 v = *(const float4*)(xb + (size_t)c * N + n4);
    float* dst = &xt[c * 33 + n4];
    dst[0] = v.x; dst[1] = v.y; dst[2] = v.z; dst[3] = v.w;
  }
  __syncthreads();

  // ---- transpose-store: full 256B rows, 2 uint4 per thread ----
  const int n = t >> 3, cg = (t & 7) * 8;
  unsigned short tmp[8];
#pragma unroll
  for (int half = 0; half < 2; half++) {
    int c8 = cg + half * 64;
#pragma unroll
    for (int j = 0; j < 8; j++) tmp[j] = f2b(xt[(c8 + j) * 33 + n]);
    *(uint4*)(xT + ((size_t)b * N + ns + n) * CD + c8) = *(uint4*)tmp;
  }
}

// ---------------------------------------------------------------------------
// K1: two block flavors, grid (68, 32):
//  x<34: qk block -- TWO y-windows (62 each) processed sequentially; Gram
//   accumulates in registers across both windows, atomics issued ONCE
//   (halves atomic traffic vs round 7). Per window: M=256 GEMM (K=128),
//   3-tap dw in-register via 16-lane shuffles (bias folded: sb, edge c0/c2),
//   post-dw q,k -> LDS only, wave=head 32x32 QK^T + norm diagonals.
//  x>=34: v block (ytile = x-34) -- proven path, writes vT.
// LDS 34,816 B, 4 blocks/CU.
// ---------------------------------------------------------------------------
__global__ __launch_bounds__(256, 4) void k1_qkv_dw(
    const unsigned short* __restrict__ xT, const unsigned short* __restrict__ qkv_wb,
    const float* __restrict__ qkv_b, const float4* __restrict__ dwq,
    const float4* __restrict__ dwq2, const float* __restrict__ c0a,
    const float* __restrict__ c2a, unsigned short* __restrict__ vT,
    float* part2)
{
  __shared__ __align__(16) char smem[34816];
  const int t = threadIdx.x;
  const int b = blockIdx.y;
  const int wv = t >> 6, l = t & 63, quad = l >> 4, lm = l & 15;

  if (blockIdx.x < 34) {
    // ==================== qk block (2 windows) ====================
    unsigned short* Bs    = (unsigned short*)smem;   // [64][136] staged rows
    unsigned short* pres2 = (unsigned short*)smem;   // [256][68] post-dw (alias)

    const unsigned short* wbase = qkv_wb + (size_t)(wv * 64 + lm) * CD + quad * 8;
    bf16x8 wa[4][4];
#pragma unroll
    for (int mt = 0; mt < 4; mt++)
#pragma unroll
      for (int ks = 0; ks < 4; ks++)
        wa[mt][ks] = *(const bf16x8*)(wbase + (size_t)mt * 16 * CD + ks * 32);

    floatx4 gqk[2][2], gqq[2], gkk[2];
#pragma unroll
    for (int a = 0; a < 2; a++) {
      gqq[a] = (floatx4){0.f, 0.f, 0.f, 0.f};
      gkk[a] = (floatx4){0.f, 0.f, 0.f, 0.f};
#pragma unroll
      for (int c = 0; c < 2; c++) gqk[a][c] = (floatx4){0.f, 0.f, 0.f, 0.f};
    }
    const int i1 = (l & 48) | ((lm + 1) & 15);
    const int i2 = (l & 48) | ((lm + 2) & 15);
    const int h = wv;

    for (int w2 = 0; w2 < 2; w2++) {
      const int win = blockIdx.x * 2 + w2;
      if (win > 66) break;                       // block-uniform
      const int ybase = win * 62;
      const bool interior = (win >= 1 && win <= 65);

      if (w2) __syncthreads();   // prev Gram reads done before restaging

      // stage rows i=0..63 <-> y = ybase-1+i (zero outside [0,N))
      if (interior) {
#pragma unroll
        for (int i = 0; i < 4; i++) {
          int f = i * 256 + t;
          int row = f >> 4, c8 = (f & 15) * 8;
          *(uint4*)&Bs[row * 136 + c8] =
              *(const uint4*)(xT + ((size_t)b * N + ybase - 1 + row) * CD + c8);
        }
      } else {
#pragma unroll
        for (int i = 0; i < 4; i++) {
          int f = i * 256 + t;
          int row = f >> 4, c8 = (f & 15) * 8;
          int yg = ybase - 1 + row;
          uint4 v = make_uint4(0u, 0u, 0u, 0u);
          if (yg >= 0 && yg < N)
            v = *(const uint4*)(xT + ((size_t)b * N + yg) * CD + c8);
          *(uint4*)&Bs[row * 136 + c8] = v;
        }
      }
      __syncthreads();

      floatx4 acc[4][4];
#pragma unroll
      for (int mt = 0; mt < 4; mt++)
#pragma unroll
        for (int nt = 0; nt < 4; nt++)
          acc[mt][nt] = (floatx4){0.f, 0.f, 0.f, 0.f};

#pragma unroll
      for (int ks = 0; ks < 4; ks++) {
        bf16x8 bb[4];
#pragma unroll
        for (int nt = 0; nt < 4; nt++)
          bb[nt] = *(const bf16x8*)&Bs[(nt * 16 + lm) * 136 + ks * 32 + quad * 8];
#pragma unroll
        for (int mt = 0; mt < 4; mt++)
#pragma unroll
          for (int nt = 0; nt < 4; nt++)
            acc[mt][nt] = MFMA16(wa[mt][ks], bb[nt], acc[mt][nt]);
      }
      __syncthreads();   // all waves done with Bs before pres2 (alias) writes

      // in-register dw: post[p] = w0*g[p] + w1*g[p+1] + w2*g[p+2] + sb
#pragma unroll
      for (int mt = 0; mt < 4; mt++) {
#pragma unroll
        for (int r = 0; r < 4; r++) {
          int o = wv * 64 + mt * 16 + quad * 4 + r;
          float4 wq = dwq2[o];
          float cc0 = 0.f, cc2 = 0.f;
          if (win == 0)  cc0 = c0a[o];
          if (win == 66) cc2 = c2a[o];
          float vv[5], r1[5], r2[5];
#pragma unroll
          for (int nt = 0; nt < 4; nt++) vv[nt] = acc[mt][nt][r];
          vv[4] = 0.f;
#pragma unroll
          for (int nt = 0; nt < 4; nt++) {
            r1[nt] = __shfl(vv[nt], i1);
            r2[nt] = __shfl(vv[nt], i2);
          }
          r1[4] = 0.f; r2[4] = 0.f;
#pragma unroll
          for (int nt = 0; nt < 4; nt++) {
            int p = nt * 16 + lm;
            int y = ybase + p;
            float g1 = (lm == 15) ? r1[nt + 1] : r1[nt];
            float g2 = (lm >= 14) ? r2[nt + 1] : r2[nt];
            float val = wq.x * vv[nt] + wq.y * g1 + wq.z * g2 + wq.w;
            if (y == 0)     val -= cc0;
            if (y == N - 1) val -= cc2;
            bool ok = (p < 62) && (y < N);
            pres2[o * 68 + p] = f2b(ok ? val : 0.f);
          }
        }
      }
      __syncthreads();

      // Gram accumulate: wave = head, K=64 (cols 62,63 are zeros)
      const unsigned short* pq = pres2 + (size_t)(h * 32) * 68;
      const unsigned short* pk = pres2 + (size_t)(128 + h * 32) * 68;
#pragma unroll
      for (int kc = 0; kc < 2; kc++) {
        bf16x8 qf[2], kf[2];
#pragma unroll
        for (int tt = 0; tt < 2; tt++) {
          qf[tt] = *(const bf16x8*)&pq[(tt * 16 + lm) * 68 + kc * 32 + quad * 8];
          kf[tt] = *(const bf16x8*)&pk[(tt * 16 + lm) * 68 + kc * 32 + quad * 8];
        }
#pragma unroll
        for (int tq = 0; tq < 2; tq++)
#pragma unroll
          for (int tk = 0; tk < 2; tk++)
            gqk[tq][tk] = MFMA16(qf[tq], kf[tk], gqk[tq][tk]);
        gqq[0] = MFMA16(qf[0], qf[0], gqq[0]);
        gqq[1] = MFMA16(qf[1], qf[1], gqq[1]);
        gkk[0] = MFMA16(kf[0], kf[0], gkk[0]);
        gkk[1] = MFMA16(kf[1], kf[1], gkk[1]);
      }
    }

    float* pp = part2 + ((size_t)b * H_ + h) * 1088;
#pragma unroll
    for (int tq = 0; tq < 2; tq++)
#pragma unroll
      for (int tk = 0; tk < 2; tk++)
#pragma unroll
        for (int r = 0; r < 4; r++)
          atomicAdd(&pp[(tq * 16 + quad * 4 + r) * 32 + tk * 16 + lm],
                    gqk[tq][tk][r]);
    if (quad == (lm >> 2)) {
      int r = lm & 3;
      atomicAdd(&pp[1024 + lm],      gqq[0][r]);
      atomicAdd(&pp[1024 + 16 + lm], gqq[1][r]);
      atomicAdd(&pp[1056 + lm],      gkk[0][r]);
      atomicAdd(&pp[1056 + 16 + lm], gkk[1][r]);
    }
  } else {
    // ==================== v block (proven path) ====================
    unsigned short* Bs   = (unsigned short*)smem;   // [128][136]
    unsigned short* pres = (unsigned short*)smem;   // [i][o] stride 132 (alias)
    const int ytile = blockIdx.x - 34;
    const int obase = 256;
    const int ybase = ytile * 124;
    const bool interior = (ytile >= 1 && ytile <= 32);

    const unsigned short* wbase =
        qkv_wb + (size_t)(obase + wv * 32 + lm) * CD + quad * 8;
    bf16x8 wa0[4], wa1[4];
#pragma unroll
    for (int ks = 0; ks < 4; ks++) {
      wa0[ks] = *(const bf16x8*)(wbase + ks * 32);
      wa1[ks] = *(const bf16x8*)(wbase + 16 * CD + ks * 32);
    }

    if (interior) {
#pragma unroll
      for (int i = 0; i < 8; i++) {
        int f = i * 256 + t;
        int row = f >> 4, c8 = (f & 15) * 8;
        *(uint4*)&Bs[row * 136 + c8] =
            *(const uint4*)(xT + ((size_t)b * N + ybase - 2 + row) * CD + c8);
      }
    } else {
#pragma unroll
      for (int i = 0; i < 8; i++) {
        int f = i * 256 + t;
        int row = f >> 4, c8 = (f & 15) * 8;
        int yg = ybase - 2 + row;
        uint4 v = make_uint4(0u, 0u, 0u, 0u);
        if (yg >= 0 && yg < N)
          v = *(const uint4*)(xT + ((size_t)b * N + yg) * CD + c8);
        *(uint4*)&Bs[row * 136 + c8] = v;
      }
    }
    __syncthreads();

    floatx4 acc[2][8];
#pragma unroll
    for (int mt = 0; mt < 2; mt++)
#pragma unroll
      for (int nt = 0; nt < 8; nt++) acc[mt][nt] = (floatx4){0.f, 0.f, 0.f, 0.f};

#pragma unroll
    for (int ks = 0; ks < 4; ks++) {
#pragma unroll
      for (int nt = 0; nt < 8; nt++) {
        bf16x8 bb = *(const bf16x8*)&Bs[(nt * 16 + lm) * 136 + ks * 32 + quad * 8];
        acc[0][nt] = MFMA16(wa0[ks], bb, acc[0][nt]);
        acc[1][nt] = MFMA16(wa1[ks], bb, acc[1][nt]);
      }
    }

    const int op = t & 63, quarter = t >> 6;
    const int o0 = 2 * op;
    const float4 wqa = dwq[256 + o0];
    const float4 wqb = dwq[256 + o0 + 1];
    __syncthreads();
    if (interior) {
#pragma unroll
      for (int mt = 0; mt < 2; mt++)
#pragma unroll
        for (int r = 0; r < 4; r++) {
          int o2 = wv * 32 + mt * 16 + quad * 4 + r;
          float bias = qkv_b[obase + o2];
#pragma unroll
          for (int nt = 0; nt < 8; nt++) {
            int i = nt * 16 + lm;
            pres[i * 132 + o2] = f2b(acc[mt][nt][r] + bias);
          }
        }
    } else {
#pragma unroll
      for (int mt = 0; mt < 2; mt++)
#pragma unroll
        for (int r = 0; r < 4; r++) {
          int o2 = wv * 32 + mt * 16 + quad * 4 + r;
          float bias = qkv_b[obase + o2];
#pragma unroll
          for (int nt = 0; nt < 8; nt++) {
            int i = nt * 16 + lm;
            int yg = ybase - 2 + i;
            pres[i * 132 + o2] =
                f2b((yg >= 0 && yg < N) ? (acc[mt][nt][r] + bias) : 0.f);
          }
        }
    }
    __syncthreads();
    const unsigned int* pu = (const unsigned int*)pres;   // [i][o-pair]
    int i0 = 2 + quarter * 31;
    unsigned int pm = pu[(i0 - 1) * 66 + op];
    unsigned int pc = pu[i0 * 66 + op];
    if (interior) {
      for (int i = i0; i < i0 + 31; i++) {
        unsigned int pp2 = pu[(i + 1) * 66 + op];
        int yo = ybase - 2 + i;
        float a0 = wqa.x * b2f(pm) + wqa.y * b2f(pc) + wqa.z * b2f(pp2) + wqa.w;
        float a1 = wqb.x * b2fh(pm) + wqb.y * b2fh(pc) + wqb.z * b2fh(pp2) + wqb.w;
        unsigned int pk2 = (unsigned int)f2b(a0) | ((unsigned int)f2b(a1) << 16);
        *(unsigned int*)(vT + ((size_t)b * N + yo) * CD + o0) = pk2;
        pm = pc; pc = pp2;
      }
    } else {
      for (int i = i0; i < i0 + 31; i++) {
        unsigned int pp2 = pu[(i + 1) * 66 + op];
        int yo = ybase - 2 + i;
        if (yo >= 0 && yo < N) {
          float a0 = wqa.x * b2f(pm) + wqa.y * b2f(pc) + wqa.z * b2f(pp2) + wqa.w;
          float a1 = wqb.x * b2fh(pm) + wqb.y * b2fh(pc) + wqb.z * b2fh(pp2) + wqb.w;
          unsigned int pk2 = (unsigned int)f2b(a0) | ((unsigned int)f2b(a1) << 16);
          *(unsigned int*)(vT + ((size_t)b * N + yo) * CD + o0) = pk2;
        }
        pm = pc; pc = pp2;
      }
    }
  }
}

// ---------------------------------------------------------------------------
// K45: read fully-reduced Gram part2[b][h][1088], normalize+temperature,
// exact stable top-k ranks, fold 4 masked softmaxes -> AwtT bf16;
// M = proj_w @ blockdiag(A) via MFMA. grid (B), 256 thr.
// ---------------------------------------------------------------------------
__global__ __launch_bounds__(256) void k45(
    const float* __restrict__ part2, const unsigned short* __restrict__ proj_wb,
    const float* __restrict__ temperature, const float* __restrict__ attn_w,
    unsigned short* __restrict__ Mb)
{
  __shared__ float La[H_][C_][33];
  __shared__ float sq2[256];
  __shared__ float rn[256];
  __shared__ float exL[H_][C_][33];
  __shared__ unsigned char rkL[H_][C_][C_];
  __shared__ unsigned short AwtT[H_][C_][40];
  const int b = blockIdx.x, t = threadIdx.x;

  const float* pbb = part2 + (size_t)b * H_ * 1088;
#pragma unroll
  for (int h = 0; h < H_; h++)
    for (int idx = t; idx < 1088; idx += 256) {
      float s = pbb[h * 1088 + idx];
      if (idx < 1024) La[h][idx >> 5][idx & 31] = s;
      else if (idx < 1056) sq2[h * 32 + (idx - 1024)] = s;
      else sq2[128 + h * 32 + (idx - 1056)] = s;
    }
  __syncthreads();
  rn[t] = 1.f / fmaxf(sqrtf(sq2[t]), 1e-12f);
  __syncthreads();
  for (int e = t; e < 4096; e += 256) {
    int h = e >> 10, i = (e >> 5) & 31, j = e & 31;
    La[h][i][j] *= rn[h * 32 + i] * rn[128 + h * 32 + j] * temperature[h];
  }
  __syncthreads();

  if (t < 128) {
    int h = t >> 5, i = t & 31;
    float m = -1e30f;
    for (int j = 0; j < 32; j++) m = fmaxf(m, La[h][i][j]);
    float S0 = 0.f, S1 = 0.f, S2 = 0.f, S3 = 0.f;
    for (int j = 0; j < 32; j++) {
      float vj = La[h][i][j];
      int r = 0;
      for (int j2 = 0; j2 < 32; j2++) {
        float v2 = La[h][i][j2];
        r += (v2 > vj) || (v2 == vj && j2 < j);
      }
      float e = __expf(vj - m);
      exL[h][i][j] = e;
      rkL[h][i][j] = (unsigned char)r;
      if (r < 16) S0 += e;
      if (r < 21) S1 += e;
      if (r < 24) S2 += e;
      if (r < 25) S3 += e;
    }
    float w0 = attn_w[0] / S0, w1 = attn_w[1] / S1;
    float w2 = attn_w[2] / S2, w3 = attn_w[3] / S3;
    for (int j = 0; j < 32; j++) {
      int r = rkL[h][i][j];
      float cmb = (r < 16 ? w0 : 0.f) + (r < 21 ? w1 : 0.f) +
                  (r < 24 ? w2 : 0.f) + (r < 25 ? w3 : 0.f);
      AwtT[h][j][i] = f2b(exL[h][i][j] * cmb);
    }
  }
  __syncthreads();

  {
    const int wv = t >> 6, l = t & 63, quad = l >> 4, lm = l & 15;
    const int h = wv;
    bf16x8 bfr[2];
#pragma unroll
    for (int jt = 0; jt < 2; jt++)
      bfr[jt] = *(const bf16x8*)&AwtT[h][jt * 16 + lm][quad * 8];
#pragma unroll
    for (int mt = 0; mt < 8; mt++) {
      bf16x8 a = *(const bf16x8*)(proj_wb +
                    (size_t)(mt * 16 + lm) * CD + h * C_ + quad * 8);
#pragma unroll
      for (int jt = 0; jt < 2; jt++) {
        floatx4 acc = (floatx4){0.f, 0.f, 0.f, 0.f};
        acc = MFMA16(a, bfr[jt], acc);
#pragma unroll
        for (int r = 0; r < 4; r++) {
          int row = quad * 4 + r;
          Mb[(size_t)b * 16384 + (mt * 16 + row) * CD + h * C_ + jt * 16 + lm] =
              f2b(acc[r]);
        }
      }
    }
  }
}

// ---------------------------------------------------------------------------
// K6: out[b] = Mb @ V^T + proj_b. A (Mb) per-ks from global (L2-hot);
// LDS = Bs only -> 4 blocks/CU. grid (32, 32), 256 thr.
// ---------------------------------------------------------------------------
__global__ __launch_bounds__(256, 4) void k6_out(
    const unsigned short* __restrict__ vT, const unsigned short* __restrict__ Mb,
    const float* __restrict__ proj_b, float* __restrict__ out)
{
  __shared__ unsigned short Bs[128 * 136];
  const int t = threadIdx.x;
  const int y0 = blockIdx.x * 128, b = blockIdx.y;
  const int wv = t >> 6, l = t & 63, quad = l >> 4, lm = l & 15;

#pragma unroll
  for (int i = 0; i < 8; i++) {
    int f = i * 256 + t;
    int row = f >> 4, c8 = (f & 15) * 8;
    *(uint4*)&Bs[row * 136 + c8] =
        *(const uint4*)(vT + ((size_t)b * N + y0 + row) * CD + c8);
  }
  __syncthreads();

  floatx4 acc[2][8];
#pragma unroll
  for (int mt = 0; mt < 2; mt++)
#pragma unroll
    for (int nt = 0; nt < 8; nt++) acc[mt][nt] = (floatx4){0.f, 0.f, 0.f, 0.f};

  const unsigned short* mbase =
      Mb + (size_t)b * 16384 + (size_t)(wv * 32 + lm) * CD + quad * 8;
#pragma unroll
  for (int ks = 0; ks < 4; ks++) {
    bf16x8 a0 = *(const bf16x8*)(mbase + ks * 32);
    bf16x8 a1 = *(const bf16x8*)(mbase + 16 * CD + ks * 32);
#pragma unroll
    for (int nt = 0; nt < 8; nt++) {
      bf16x8 bb = *(const bf16x8*)&Bs[(nt * 16 + lm) * 136 + ks * 32 + quad * 8];
      acc[0][nt] = MFMA16(a0, bb, acc[0][nt]);
      acc[1][nt] = MFMA16(a1, bb, acc[1][nt]);
    }
  }

#pragma unroll
  for (int mt = 0; mt < 2; mt++)
#pragma unroll
    for (int r = 0; r < 4; r++) {
      int o = wv * 32 + mt * 16 + quad * 4 + r;
      float pb = proj_b[o];
#pragma unroll
      for (int nt = 0; nt < 8; nt++) {
        int y = y0 + nt * 16 + lm;
        out[((size_t)b * CD + o) * N + y] = acc[mt][nt][r] + pb;
      }
    }
}

extern "C" void kernel_launch(void* const* d_in, const int* in_sizes, int n_in,
                              void* d_out, int out_size, void* d_ws, size_t ws_size,
                              hipStream_t stream)
{
  (void)in_sizes; (void)n_in; (void)out_size; (void)ws_size;
  const float* x           = (const float*)d_in[0];
  const float* qkv_w       = (const float*)d_in[1];
  const float* qkv_b       = (const float*)d_in[2];
  const float* dw_w        = (const float*)d_in[3];
  const float* dw_b        = (const float*)d_in[4];
  const float* proj_w      = (const float*)d_in[5];
  const float* proj_b      = (const float*)d_in[6];
  const float* temperature = (const float*)d_in[7];
  const float* attn_w      = (const float*)d_in[8];
  float* out = (float*)d_out;

  unsigned short* xT      = (unsigned short*)d_ws;   // 16,777,216 sh
  unsigned short* qkv_wb  = xT + (size_t)16777216;   //     49,152
  unsigned short* proj_wb = qkv_wb + 49152;          //     16,384
  unsigned short* hole    = proj_wb + 16384;         // (old qkvd slot, unused)
  unsigned short* vT      = hole + (size_t)33554432; // 16,777,216
  unsigned short* Mb      = vT + (size_t)16777216;   //    524,288
  float* part2 = (float*)(Mb + 524288);              //    139,264 f (557 KB)
  // Coefficient tables alias Mb (written k0, read k1, dead before k45's Mb):
  float4* dwq  = (float4*)Mb;                        // 384 f4
  float4* dwq2 = (float4*)(Mb + 3072);               // 256 f4
  float*  c0a  = (float*)(Mb + 5120);                // 256 f
  float*  c2a  = (float*)(Mb + 5632);                // 256 f

  k0_xt    <<<dim3(128, 32),  256, 0, stream>>>(x, xT, qkv_w, proj_w, dw_w,
                                                dw_b, qkv_b, qkv_wb, proj_wb,
                                                dwq, dwq2, c0a, c2a, part2);
  k1_qkv_dw<<<dim3(68, 32),   256, 0, stream>>>(xT, qkv_wb, qkv_b, dwq, dwq2,
                                                c0a, c2a, vT, part2);
  k45      <<<dim3(B_),       256, 0, stream>>>(part2, proj_wb, temperature,
                                                attn_w, Mb);
  k6_out   <<<dim3(32, B_),   256, 0, stream>>>(vT, Mb, proj_b, out);
}

// Round 9
// 237.752 us; speedup vs baseline: 1.2782x; 1.2782x over previous
//
#include <hip/hip_runtime.h>

#define B_ 32
#define CD 128
#define O3 384
#define N  4096
#define H_ 4
#define C_ 32

typedef __bf16 bf16x8 __attribute__((ext_vector_type(8)));
typedef float floatx4 __attribute__((ext_vector_type(4)));

#define MFMA16(a, b, c) __builtin_amdgcn_mfma_f32_16x16x32_bf16(a, b, c, 0, 0, 0)

__device__ __forceinline__ float b2f(unsigned int u) {   // low 16 bits
  return __builtin_bit_cast(float, u << 16);
}
__device__ __forceinline__ float b2fh(unsigned int u) {  // high 16 bits
  return __builtin_bit_cast(float, u & 0xffff0000u);
}
__device__ __forceinline__ unsigned short f2b(float f) {
  unsigned int bits = __builtin_bit_cast(unsigned int, f);
  unsigned int r = (bits + 0x7FFFu + ((bits >> 16) & 1u)) >> 16;
  return (unsigned short)r;
}

// ---------------------------------------------------------------------------
// K0: transpose+convert x [b][c][n] fp32 -> xT [b][n][c] bf16.
// Block = 32-n strip x ALL 128 c -> stores full 256B xT rows (no partial-line
// write-allocate). LDS [128][33] f32. Side-work on y==0 plane: weight
// conversions (wid<66), qk coefficient tables (wid==66), part2 zeroing
// (wid 67..127). grid (128, 32), 256 thr.
// ---------------------------------------------------------------------------
__global__ __launch_bounds__(256) void k0_xt(
    const float* __restrict__ x, unsigned short* __restrict__ xT,
    const float* __restrict__ qkv_w, const float* __restrict__ proj_w,
    const float* __restrict__ dw_w, const float* __restrict__ dw_b,
    const float* __restrict__ qkv_b,
    unsigned short* __restrict__ qkv_wb, unsigned short* __restrict__ proj_wb,
    float4* __restrict__ dwq, float4* __restrict__ dwq2,
    float* __restrict__ c0a, float* __restrict__ c2a,
    float* __restrict__ part2)
{
  __shared__ float xt[128 * 33];
  const int t = threadIdx.x;
  const int ns = blockIdx.x * 32, b = blockIdx.y;
  const float* xb = x + (size_t)b * CD * N + ns;

  // ---- side work (y==0 plane) ----
  if (blockIdx.y == 0) {
    int wid = blockIdx.x;
    if (wid < 66) {
      int e = (wid * 256 + t) * 4;
      if (e < 49152) {
        float4 v = *(const float4*)(qkv_w + e);
        unsigned short tmp[4] = {f2b(v.x), f2b(v.y), f2b(v.z), f2b(v.w)};
        *(uint2*)(qkv_wb + e) = *(uint2*)tmp;
      } else if (e < 65536) {
        int off = e - 49152;
        float4 v = *(const float4*)(proj_w + off);
        unsigned short tmp[4] = {f2b(v.x), f2b(v.y), f2b(v.z), f2b(v.w)};
        *(uint2*)(proj_wb + off) = *(uint2*)tmp;
      } else {
        int o = (e - 65536) >> 2;
        if (o < 384)
          dwq[o] = make_float4(dw_w[o * 9 + 1], dw_w[o * 9 + 4],
                               dw_w[o * 9 + 7], dw_b[o]);
      }
    } else if (wid == 66) {
      int o = t;    // 256 threads cover q,k channels 0..255
      float w0 = dw_w[o * 9 + 1], w1 = dw_w[o * 9 + 4], w2 = dw_w[o * 9 + 7];
      float qb = qkv_b[o];
      dwq2[o] = make_float4(w0, w1, w2, qb * (w0 + w1 + w2) + dw_b[o]);
      c0a[o] = qb * w0;
      c2a[o] = qb * w2;
    } else {      // wid 67..127: zero part2 (34816 uint4)
      int idx = (wid - 67) * 256 + t;
      uint4 z4 = make_uint4(0u, 0u, 0u, 0u);
      for (int k2 = idx; k2 < 34816; k2 += 61 * 256)
        ((uint4*)part2)[k2] = z4;
    }
  }

  // ---- load 128 c-rows x 32 n (float4 per lane, 4 passes) ----
#pragma unroll
  for (int p = 0; p < 4; p++) {
    int c = p * 32 + (t >> 3), n4 = (t & 7) * 4;
    float4 v = *(const float4*)(xb + (size_t)c * N + n4);
    float* dst = &xt[c * 33 + n4];
    dst[0] = v.x; dst[1] = v.y; dst[2] = v.z; dst[3] = v.w;
  }
  __syncthreads();

  // ---- transpose-store: full 256B rows, 2 uint4 per thread ----
  const int n = t >> 3, cg = (t & 7) * 8;
  unsigned short tmp[8];
#pragma unroll
  for (int half = 0; half < 2; half++) {
    int c8 = cg + half * 64;
#pragma unroll
    for (int j = 0; j < 8; j++) tmp[j] = f2b(xt[(c8 + j) * 33 + n]);
    *(uint4*)(xT + ((size_t)b * N + ns + n) * CD + c8) = *(uint4*)tmp;
  }
}

// ---------------------------------------------------------------------------
// K1: two block flavors, grid (101, 32) -- ROUND-7 structure (proven 67 us;
// round-8's 2-window + bounds-4 variant spilled to scratch and regressed).
//  x<67: qk block (M=256, y-window 62, K=128). Raw GEMM into regs, 3-tap dw
//   in-register via 16-lane shuffles (bias folded: sb, edge c0/c2), post-dw
//   q,k -> LDS only; wave=head 32x32 QK^T + norm diagonals; atomicAdd the
//   1088-float partial into part2[b][h]. q,k never touch HBM.
//  x>=67: v block (window 124, obase=256), writes vT.
// LDS 34,816 B, bounds (256,3).
// ---------------------------------------------------------------------------
__global__ __launch_bounds__(256, 3) void k1_qkv_dw(
    const unsigned short* __restrict__ xT, const unsigned short* __restrict__ qkv_wb,
    const float* __restrict__ qkv_b, const float4* __restrict__ dwq,
    const float4* __restrict__ dwq2, const float* __restrict__ c0a,
    const float* __restrict__ c2a, unsigned short* __restrict__ vT,
    float* part2)
{
  __shared__ __align__(16) char smem[34816];
  const int t = threadIdx.x;
  const int b = blockIdx.y;
  const int wv = t >> 6, l = t & 63, quad = l >> 4, lm = l & 15;

  if (blockIdx.x < 67) {
    // ==================== qk block ====================
    unsigned short* Bs    = (unsigned short*)smem;   // [64][136] staged rows
    unsigned short* pres2 = (unsigned short*)smem;   // [256][68] post-dw (alias)
    const int yw = blockIdx.x;
    const int ybase = yw * 62;
    const bool interior = (yw >= 1 && yw <= 65);

    const unsigned short* wbase = qkv_wb + (size_t)(wv * 64 + lm) * CD + quad * 8;
    bf16x8 wa[4][4];
#pragma unroll
    for (int mt = 0; mt < 4; mt++)
#pragma unroll
      for (int ks = 0; ks < 4; ks++)
        wa[mt][ks] = *(const bf16x8*)(wbase + (size_t)mt * 16 * CD + ks * 32);

    // stage rows i=0..63 <-> y = ybase-1+i (zero outside [0,N))
    if (interior) {
#pragma unroll
      for (int i = 0; i < 4; i++) {
        int f = i * 256 + t;
        int row = f >> 4, c8 = (f & 15) * 8;
        *(uint4*)&Bs[row * 136 + c8] =
            *(const uint4*)(xT + ((size_t)b * N + ybase - 1 + row) * CD + c8);
      }
    } else {
#pragma unroll
      for (int i = 0; i < 4; i++) {
        int f = i * 256 + t;
        int row = f >> 4, c8 = (f & 15) * 8;
        int yg = ybase - 1 + row;
        uint4 v = make_uint4(0u, 0u, 0u, 0u);
        if (yg >= 0 && yg < N)
          v = *(const uint4*)(xT + ((size_t)b * N + yg) * CD + c8);
        *(uint4*)&Bs[row * 136 + c8] = v;
      }
    }
    __syncthreads();

    floatx4 acc[4][4];
#pragma unroll
    for (int mt = 0; mt < 4; mt++)
#pragma unroll
      for (int nt = 0; nt < 4; nt++) acc[mt][nt] = (floatx4){0.f, 0.f, 0.f, 0.f};

#pragma unroll
    for (int ks = 0; ks < 4; ks++) {
      bf16x8 bb[4];
#pragma unroll
      for (int nt = 0; nt < 4; nt++)
        bb[nt] = *(const bf16x8*)&Bs[(nt * 16 + lm) * 136 + ks * 32 + quad * 8];
#pragma unroll
      for (int mt = 0; mt < 4; mt++)
#pragma unroll
        for (int nt = 0; nt < 4; nt++)
          acc[mt][nt] = MFMA16(wa[mt][ks], bb[nt], acc[mt][nt]);
    }
    __syncthreads();   // all waves done reading Bs before pres2 (alias) writes

    // in-register dw: post[p] = w0*g[p] + w1*g[p+1] + w2*g[p+2] + sb
    const int i1 = (l & 48) | ((lm + 1) & 15);
    const int i2 = (l & 48) | ((lm + 2) & 15);
#pragma unroll
    for (int mt = 0; mt < 4; mt++) {
#pragma unroll
      for (int r = 0; r < 4; r++) {
        int o = wv * 64 + mt * 16 + quad * 4 + r;
        float4 wq = dwq2[o];
        float cc0 = 0.f, cc2 = 0.f;
        if (yw == 0)  cc0 = c0a[o];
        if (yw == 66) cc2 = c2a[o];
        float vv[5], r1[5], r2[5];
#pragma unroll
        for (int nt = 0; nt < 4; nt++) vv[nt] = acc[mt][nt][r];
        vv[4] = 0.f;
#pragma unroll
        for (int nt = 0; nt < 4; nt++) {
          r1[nt] = __shfl(vv[nt], i1);
          r2[nt] = __shfl(vv[nt], i2);
        }
        r1[4] = 0.f; r2[4] = 0.f;
#pragma unroll
        for (int nt = 0; nt < 4; nt++) {
          int p = nt * 16 + lm;
          int y = ybase + p;
          float g1 = (lm == 15) ? r1[nt + 1] : r1[nt];
          float g2 = (lm >= 14) ? r2[nt + 1] : r2[nt];
          float val = wq.x * vv[nt] + wq.y * g1 + wq.z * g2 + wq.w;
          if (y == 0)     val -= cc0;
          if (y == N - 1) val -= cc2;
          bool ok = (p < 62) && (y < N);
          pres2[o * 68 + p] = f2b(ok ? val : 0.f);
        }
      }
    }
    __syncthreads();

    // Gram: wave = head. QK^T 32x32 + q/k norm diagonals over K=64.
    const int h = wv;
    const unsigned short* pq = pres2 + (size_t)(h * 32) * 68;
    const unsigned short* pk = pres2 + (size_t)(128 + h * 32) * 68;
    floatx4 gqk[2][2], gqq[2], gkk[2];
#pragma unroll
    for (int a = 0; a < 2; a++) {
      gqq[a] = (floatx4){0.f, 0.f, 0.f, 0.f};
      gkk[a] = (floatx4){0.f, 0.f, 0.f, 0.f};
#pragma unroll
      for (int c = 0; c < 2; c++) gqk[a][c] = (floatx4){0.f, 0.f, 0.f, 0.f};
    }
#pragma unroll
    for (int kc = 0; kc < 2; kc++) {
      bf16x8 qf[2], kf[2];
#pragma unroll
      for (int tt = 0; tt < 2; tt++) {
        qf[tt] = *(const bf16x8*)&pq[(tt * 16 + lm) * 68 + kc * 32 + quad * 8];
        kf[tt] = *(const bf16x8*)&pk[(tt * 16 + lm) * 68 + kc * 32 + quad * 8];
      }
#pragma unroll
      for (int tq = 0; tq < 2; tq++)
#pragma unroll
        for (int tk = 0; tk < 2; tk++)
          gqk[tq][tk] = MFMA16(qf[tq], kf[tk], gqk[tq][tk]);
      gqq[0] = MFMA16(qf[0], qf[0], gqq[0]);
      gqq[1] = MFMA16(qf[1], qf[1], gqq[1]);
      gkk[0] = MFMA16(kf[0], kf[0], gkk[0]);
      gkk[1] = MFMA16(kf[1], kf[1], gkk[1]);
    }
    float* pp = part2 + ((size_t)b * H_ + h) * 1088;
#pragma unroll
    for (int tq = 0; tq < 2; tq++)
#pragma unroll
      for (int tk = 0; tk < 2; tk++)
#pragma unroll
        for (int r = 0; r < 4; r++)
          atomicAdd(&pp[(tq * 16 + quad * 4 + r) * 32 + tk * 16 + lm],
                    gqk[tq][tk][r]);
    if (quad == (lm >> 2)) {
      int r = lm & 3;
      atomicAdd(&pp[1024 + lm],      gqq[0][r]);
      atomicAdd(&pp[1024 + 16 + lm], gqq[1][r]);
      atomicAdd(&pp[1056 + lm],      gkk[0][r]);
      atomicAdd(&pp[1056 + 16 + lm], gkk[1][r]);
    }
  } else {
    // ==================== v block (proven path) ====================
    unsigned short* Bs   = (unsigned short*)smem;   // [128][136]
    unsigned short* pres = (unsigned short*)smem;   // [i][o] stride 132 (alias)
    const int ytile = blockIdx.x - 67;
    const int obase = 256;
    const int ybase = ytile * 124;
    const bool interior = (ytile >= 1 && ytile <= 32);

    const unsigned short* wbase =
        qkv_wb + (size_t)(obase + wv * 32 + lm) * CD + quad * 8;
    bf16x8 wa0[4], wa1[4];
#pragma unroll
    for (int ks = 0; ks < 4; ks++) {
      wa0[ks] = *(const bf16x8*)(wbase + ks * 32);
      wa1[ks] = *(const bf16x8*)(wbase + 16 * CD + ks * 32);
    }

    if (interior) {
#pragma unroll
      for (int i = 0; i < 8; i++) {
        int f = i * 256 + t;
        int row = f >> 4, c8 = (f & 15) * 8;
        *(uint4*)&Bs[row * 136 + c8] =
            *(const uint4*)(xT + ((size_t)b * N + ybase - 2 + row) * CD + c8);
      }
    } else {
#pragma unroll
      for (int i = 0; i < 8; i++) {
        int f = i * 256 + t;
        int row = f >> 4, c8 = (f & 15) * 8;
        int yg = ybase - 2 + row;
        uint4 v = make_uint4(0u, 0u, 0u, 0u);
        if (yg >= 0 && yg < N)
          v = *(const uint4*)(xT + ((size_t)b * N + yg) * CD + c8);
        *(uint4*)&Bs[row * 136 + c8] = v;
      }
    }
    __syncthreads();

    floatx4 acc[2][8];
#pragma unroll
    for (int mt = 0; mt < 2; mt++)
#pragma unroll
      for (int nt = 0; nt < 8; nt++) acc[mt][nt] = (floatx4){0.f, 0.f, 0.f, 0.f};

#pragma unroll
    for (int ks = 0; ks < 4; ks++) {
#pragma unroll
      for (int nt = 0; nt < 8; nt++) {
        bf16x8 bb = *(const bf16x8*)&Bs[(nt * 16 + lm) * 136 + ks * 32 + quad * 8];
        acc[0][nt] = MFMA16(wa0[ks], bb, acc[0][nt]);
        acc[1][nt] = MFMA16(wa1[ks], bb, acc[1][nt]);
      }
    }

    const int op = t & 63, quarter = t >> 6;
    const int o0 = 2 * op;
    const float4 wqa = dwq[256 + o0];
    const float4 wqb = dwq[256 + o0 + 1];
    __syncthreads();
    if (interior) {
#pragma unroll
      for (int mt = 0; mt < 2; mt++)
#pragma unroll
        for (int r = 0; r < 4; r++) {
          int o2 = wv * 32 + mt * 16 + quad * 4 + r;
          float bias = qkv_b[obase + o2];
#pragma unroll
          for (int nt = 0; nt < 8; nt++) {
            int i = nt * 16 + lm;
            pres[i * 132 + o2] = f2b(acc[mt][nt][r] + bias);
          }
        }
    } else {
#pragma unroll
      for (int mt = 0; mt < 2; mt++)
#pragma unroll
        for (int r = 0; r < 4; r++) {
          int o2 = wv * 32 + mt * 16 + quad * 4 + r;
          float bias = qkv_b[obase + o2];
#pragma unroll
          for (int nt = 0; nt < 8; nt++) {
            int i = nt * 16 + lm;
            int yg = ybase - 2 + i;
            pres[i * 132 + o2] =
                f2b((yg >= 0 && yg < N) ? (acc[mt][nt][r] + bias) : 0.f);
          }
        }
    }
    __syncthreads();
    const unsigned int* pu = (const unsigned int*)pres;   // [i][o-pair]
    int i0 = 2 + quarter * 31;
    unsigned int pm = pu[(i0 - 1) * 66 + op];
    unsigned int pc = pu[i0 * 66 + op];
    if (interior) {
      for (int i = i0; i < i0 + 31; i++) {
        unsigned int pp2 = pu[(i + 1) * 66 + op];
        int yo = ybase - 2 + i;
        float a0 = wqa.x * b2f(pm) + wqa.y * b2f(pc) + wqa.z * b2f(pp2) + wqa.w;
        float a1 = wqb.x * b2fh(pm) + wqb.y * b2fh(pc) + wqb.z * b2fh(pp2) + wqb.w;
        unsigned int pk2 = (unsigned int)f2b(a0) | ((unsigned int)f2b(a1) << 16);
        *(unsigned int*)(vT + ((size_t)b * N + yo) * CD + o0) = pk2;
        pm = pc; pc = pp2;
      }
    } else {
      for (int i = i0; i < i0 + 31; i++) {
        unsigned int pp2 = pu[(i + 1) * 66 + op];
        int yo = ybase - 2 + i;
        if (yo >= 0 && yo < N) {
          float a0 = wqa.x * b2f(pm) + wqa.y * b2f(pc) + wqa.z * b2f(pp2) + wqa.w;
          float a1 = wqb.x * b2fh(pm) + wqb.y * b2fh(pc) + wqb.z * b2fh(pp2) + wqb.w;
          unsigned int pk2 = (unsigned int)f2b(a0) | ((unsigned int)f2b(a1) << 16);
          *(unsigned int*)(vT + ((size_t)b * N + yo) * CD + o0) = pk2;
        }
        pm = pc; pc = pp2;
      }
    }
  }
}

// ---------------------------------------------------------------------------
// K45: read fully-reduced Gram part2[b][h][1088], normalize+temperature,
// exact stable top-k ranks, fold 4 masked softmaxes -> AwtT bf16;
// M = proj_w @ blockdiag(A) via MFMA. grid (B), 256 thr.
// ---------------------------------------------------------------------------
__global__ __launch_bounds__(256) void k45(
    const float* __restrict__ part2, const unsigned short* __restrict__ proj_wb,
    const float* __restrict__ temperature, const float* __restrict__ attn_w,
    unsigned short* __restrict__ Mb)
{
  __shared__ float La[H_][C_][33];
  __shared__ float sq2[256];
  __shared__ float rn[256];
  __shared__ float exL[H_][C_][33];
  __shared__ unsigned char rkL[H_][C_][C_];
  __shared__ unsigned short AwtT[H_][C_][40];
  const int b = blockIdx.x, t = threadIdx.x;

  const float* pbb = part2 + (size_t)b * H_ * 1088;
#pragma unroll
  for (int h = 0; h < H_; h++)
    for (int idx = t; idx < 1088; idx += 256) {
      float s = pbb[h * 1088 + idx];
      if (idx < 1024) La[h][idx >> 5][idx & 31] = s;
      else if (idx < 1056) sq2[h * 32 + (idx - 1024)] = s;
      else sq2[128 + h * 32 + (idx - 1056)] = s;
    }
  __syncthreads();
  rn[t] = 1.f / fmaxf(sqrtf(sq2[t]), 1e-12f);
  __syncthreads();
  for (int e = t; e < 4096; e += 256) {
    int h = e >> 10, i = (e >> 5) & 31, j = e & 31;
    La[h][i][j] *= rn[h * 32 + i] * rn[128 + h * 32 + j] * temperature[h];
  }
  __syncthreads();

  if (t < 128) {
    int h = t >> 5, i = t & 31;
    float m = -1e30f;
    for (int j = 0; j < 32; j++) m = fmaxf(m, La[h][i][j]);
    float S0 = 0.f, S1 = 0.f, S2 = 0.f, S3 = 0.f;
    for (int j = 0; j < 32; j++) {
      float vj = La[h][i][j];
      int r = 0;
      for (int j2 = 0; j2 < 32; j2++) {
        float v2 = La[h][i][j2];
        r += (v2 > vj) || (v2 == vj && j2 < j);
      }
      float e = __expf(vj - m);
      exL[h][i][j] = e;
      rkL[h][i][j] = (unsigned char)r;
      if (r < 16) S0 += e;
      if (r < 21) S1 += e;
      if (r < 24) S2 += e;
      if (r < 25) S3 += e;
    }
    float w0 = attn_w[0] / S0, w1 = attn_w[1] / S1;
    float w2 = attn_w[2] / S2, w3 = attn_w[3] / S3;
    for (int j = 0; j < 32; j++) {
      int r = rkL[h][i][j];
      float cmb = (r < 16 ? w0 : 0.f) + (r < 21 ? w1 : 0.f) +
                  (r < 24 ? w2 : 0.f) + (r < 25 ? w3 : 0.f);
      AwtT[h][j][i] = f2b(exL[h][i][j] * cmb);
    }
  }
  __syncthreads();

  {
    const int wv = t >> 6, l = t & 63, quad = l >> 4, lm = l & 15;
    const int h = wv;
    bf16x8 bfr[2];
#pragma unroll
    for (int jt = 0; jt < 2; jt++)
      bfr[jt] = *(const bf16x8*)&AwtT[h][jt * 16 + lm][quad * 8];
#pragma unroll
    for (int mt = 0; mt < 8; mt++) {
      bf16x8 a = *(const bf16x8*)(proj_wb +
                    (size_t)(mt * 16 + lm) * CD + h * C_ + quad * 8);
#pragma unroll
      for (int jt = 0; jt < 2; jt++) {
        floatx4 acc = (floatx4){0.f, 0.f, 0.f, 0.f};
        acc = MFMA16(a, bfr[jt], acc);
#pragma unroll
        for (int r = 0; r < 4; r++) {
          int row = quad * 4 + r;
          Mb[(size_t)b * 16384 + (mt * 16 + row) * CD + h * C_ + jt * 16 + lm] =
              f2b(acc[r]);
        }
      }
    }
  }
}

// ---------------------------------------------------------------------------
// K6: out[b] = Mb @ V^T + proj_b. A (Mb) per-ks from global (L2-hot).
// NEW epilogue: per mt-half, scatter acc+bias into [64][132] f32 LDS tile
// (aliases Bs, dead after MFMA loop; <=2-way banks) then 32-lane float4 row
// sweeps -> 512B fully-contiguous out stores (was 64B segments).
// LDS 34,816 B -> 4 blocks/CU. grid (32, 32), 256 thr.
// ---------------------------------------------------------------------------
__global__ __launch_bounds__(256, 4) void k6_out(
    const unsigned short* __restrict__ vT, const unsigned short* __restrict__ Mb,
    const float* __restrict__ proj_b, float* __restrict__ out)
{
  __shared__ __align__(16) char smem6[34816];
  unsigned short* Bs = (unsigned short*)smem6;   // [128][136] staged vT rows
  float* fs = (float*)smem6;                     // [64][132] out rows (alias)
  const int t = threadIdx.x;
  const int y0 = blockIdx.x * 128, b = blockIdx.y;
  const int wv = t >> 6, l = t & 63, quad = l >> 4, lm = l & 15;

#pragma unroll
  for (int i = 0; i < 8; i++) {
    int f = i * 256 + t;
    int row = f >> 4, c8 = (f & 15) * 8;
    *(uint4*)&Bs[row * 136 + c8] =
        *(const uint4*)(vT + ((size_t)b * N + y0 + row) * CD + c8);
  }
  __syncthreads();

  floatx4 acc[2][8];
#pragma unroll
  for (int mt = 0; mt < 2; mt++)
#pragma unroll
    for (int nt = 0; nt < 8; nt++) acc[mt][nt] = (floatx4){0.f, 0.f, 0.f, 0.f};

  const unsigned short* mbase =
      Mb + (size_t)b * 16384 + (size_t)(wv * 32 + lm) * CD + quad * 8;
#pragma unroll
  for (int ks = 0; ks < 4; ks++) {
    bf16x8 a0 = *(const bf16x8*)(mbase + ks * 32);
    bf16x8 a1 = *(const bf16x8*)(mbase + 16 * CD + ks * 32);
#pragma unroll
    for (int nt = 0; nt < 8; nt++) {
      bf16x8 bb = *(const bf16x8*)&Bs[(nt * 16 + lm) * 136 + ks * 32 + quad * 8];
      acc[0][nt] = MFMA16(a0, bb, acc[0][nt]);
      acc[1][nt] = MFMA16(a1, bb, acc[1][nt]);
    }
  }

  // epilogue: two halves; LDS-staged transpose to 512B-contiguous stores
  const int srow = t >> 5, lane32 = t & 31;
#pragma unroll
  for (int mt = 0; mt < 2; mt++) {
    __syncthreads();   // Bs reads (mt=0) / previous half's LDS reads (mt=1)
#pragma unroll
    for (int r = 0; r < 4; r++) {
      int lrow = wv * 16 + quad * 4 + r;
      int o = wv * 32 + mt * 16 + quad * 4 + r;
      float pb = proj_b[o];
#pragma unroll
      for (int nt = 0; nt < 8; nt++)
        fs[lrow * 132 + nt * 16 + lm] = acc[mt][nt][r] + pb;
    }
    __syncthreads();
#pragma unroll
    for (int pass = 0; pass < 8; pass++) {
      int s = pass * 8 + srow;
      int o = (s >> 4) * 32 + mt * 16 + (s & 15);
      float4 vv = *(float4*)&fs[s * 132 + lane32 * 4];
      *(float4*)&out[((size_t)b * CD + o) * N + y0 + lane32 * 4] = vv;
    }
  }
}

extern "C" void kernel_launch(void* const* d_in, const int* in_sizes, int n_in,
                              void* d_out, int out_size, void* d_ws, size_t ws_size,
                              hipStream_t stream)
{
  (void)in_sizes; (void)n_in; (void)out_size; (void)ws_size;
  const float* x           = (const float*)d_in[0];
  const float* qkv_w       = (const float*)d_in[1];
  const float* qkv_b       = (const float*)d_in[2];
  const float* dw_w        = (const float*)d_in[3];
  const float* dw_b        = (const float*)d_in[4];
  const float* proj_w      = (const float*)d_in[5];
  const float* proj_b      = (const float*)d_in[6];
  const float* temperature = (const float*)d_in[7];
  const float* attn_w      = (const float*)d_in[8];
  float* out = (float*)d_out;

  unsigned short* xT      = (unsigned short*)d_ws;   // 16,777,216 sh
  unsigned short* qkv_wb  = xT + (size_t)16777216;   //     49,152
  unsigned short* proj_wb = qkv_wb + 49152;          //     16,384
  unsigned short* hole    = proj_wb + 16384;         // (old qkvd slot, unused)
  unsigned short* vT      = hole + (size_t)33554432; // 16,777,216
  unsigned short* Mb      = vT + (size_t)16777216;   //    524,288
  float* part2 = (float*)(Mb + 524288);              //    139,264 f (557 KB)
  // Coefficient tables alias Mb (written k0, read k1, dead before k45's Mb):
  float4* dwq  = (float4*)Mb;                        // 384 f4
  float4* dwq2 = (float4*)(Mb + 3072);               // 256 f4
  float*  c0a  = (float*)(Mb + 5120);                // 256 f
  float*  c2a  = (float*)(Mb + 5632);                // 256 f

  k0_xt    <<<dim3(128, 32),  256, 0, stream>>>(x, xT, qkv_w, proj_w, dw_w,
                                                dw_b, qkv_b, qkv_wb, proj_wb,
                                                dwq, dwq2, c0a, c2a, part2);
  k1_qkv_dw<<<dim3(101, 32),  256, 0, stream>>>(xT, qkv_wb, qkv_b, dwq, dwq2,
                                                c0a, c2a, vT, part2);
  k45      <<<dim3(B_),       256, 0, stream>>>(part2, proj_wb, temperature,
                                                attn_w, Mb);
  k6_out   <<<dim3(32, B_),   256, 0, stream>>>(vT, Mb, proj_b, out);
}